// Round 16
// baseline (37.374 us; speedup 1.0000x reference)
//
#include <hip/hip_runtime.h>

#define BATCH 2048
#define NSTEP 14
#define NSLOT 224
#define UCHUNKS (NSTEP * 3 * 64)   // 2688 16B chunks = 43008 B

typedef __attribute__((ext_vector_type(8))) short s16x8;
typedef __attribute__((ext_vector_type(16))) float f32x16;
typedef __attribute__((ext_vector_type(4))) int i32x4;

// ---- slot table: k-slot -> monomial, permuted so slot pairs (t, t+8) share (a,b) ----
// Single source of truth for BOTH prep (U layout) and kernel (monomial build).
struct SlotTab { signed char ty[NSLOT], a[NSLOT], b[NSLOT], c[NSLOT]; };
constexpr SlotTab make_slots() {
  SlotTab st{};
  for (int q = 0; q < NSLOT; q++) { st.ty[q] = 0; st.a[q] = 0; st.b[q] = 0; st.c[q] = 0; }
  int ta[165], tb[165], tc[165]; int nt = 0;
  for (int a = 0; a < 9; a++) for (int b = a; b < 9; b++) for (int c = b; c < 9; c++) {
    ta[nt] = a; tb[nt] = b; tc[nt] = c; nt++;
  }
  // pair consecutive same-(a,b) triples (70 pairs, 25 singles)
  int p0[83], p1[83]; int np = 0;
  int sing[165]; int ns = 0;
  {
    int i = 0;
    while (i < 165) {
      if (i + 1 < 165 && ta[i] == ta[i + 1] && tb[i] == tb[i + 1]) { p0[np] = i; p1[np] = i + 1; np++; i += 2; }
      else { sing[ns++] = i; i++; }
    }
  }
  for (int j = 0; j < np; j++) {            // paired triples at (s*16+t, s*16+8+t)
    int s = j / 8, t = j % 8;
    int q0 = s * 16 + t, q1 = s * 16 + 8 + t;
    st.ty[q0] = 3; st.a[q0] = (signed char)ta[p0[j]]; st.b[q0] = (signed char)tb[p0[j]]; st.c[q0] = (signed char)tc[p0[j]];
    st.ty[q1] = 3; st.a[q1] = (signed char)ta[p1[j]]; st.b[q1] = (signed char)tb[p1[j]]; st.c[q1] = (signed char)tc[p1[j]];
  }
  // remaining 84 slots: 25 single triples, 45 deg2 pairs, 9 linear, 5 zero
  int ity[84], ia[84], ib[84], ic[84]; int ni = 0;
  for (int j = 0; j < ns; j++) { ity[ni] = 3; ia[ni] = ta[sing[j]]; ib[ni] = tb[sing[j]]; ic[ni] = tc[sing[j]]; ni++; }
  for (int a = 0; a < 9; a++) for (int b = a; b < 9; b++) { ity[ni] = 2; ia[ni] = a; ib[ni] = b; ic[ni] = 0; ni++; }
  for (int i = 0; i < 9; i++) { ity[ni] = 1; ia[ni] = i; ib[ni] = 0; ic[ni] = 0; ni++; }
  while (ni < 84) { ity[ni] = 0; ia[ni] = 0; ib[ni] = 0; ic[ni] = 0; ni++; }
  for (int j = 0; j < 84; j++) {
    int pos = np + j / 2;
    int s = pos / 8, t = pos % 8;
    int q = s * 16 + (j % 2) * 8 + t;
    st.ty[q] = (signed char)ity[j]; st.a[q] = (signed char)ia[j]; st.b[q] = (signed char)ib[j]; st.c[q] = (signed char)ic[j];
  }
  return st;
}
constexpr SlotTab SLOTS = make_slots();

// ---- prep: build bf16 U^T table in A-fragment-major order per SLOTS ----
__global__ void prep_kernel(const float* __restrict__ U30, const float* __restrict__ U20, const float* __restrict__ U10,
                            const float* __restrict__ U31, const float* __restrict__ U21, const float* __restrict__ U11,
                            const float* __restrict__ U32, const float* __restrict__ U22, const float* __restrict__ U12,
                            unsigned short* __restrict__ wsB) {
  int t = blockIdx.x * blockDim.x + threadIdx.x;
  if (t >= UCHUNKS * 8) return;
  int j = t & 7;
  int lane = (t >> 3) & 63;
  int cf = t >> 9;                 // s*3+ct
  int s = cf / 3, ct = cf % 3;
  int n = ct * 32 + (lane & 31);
  int k = s * 16 + (lane >> 5) * 8 + j;
  const float* U3[3] = {U30, U31, U32};
  const float* U2[3] = {U20, U21, U22};
  const float* U1[3] = {U10, U11, U12};
  const int ty = SLOTS.ty[k], a = SLOTS.a[k], b = SLOTS.b[k], cc = SLOTS.c[k];
  float val = 0.f;
  if (ty == 3 && n < 54) {
    int o = n / 6, j3 = n % 6;
    int ir = (o > 0) + (o > 3); int lo = o - (ir == 1 ? 1 : (ir == 2 ? 4 : 0));
    int pm[6][3] = {{a,b,cc},{a,cc,b},{b,a,cc},{b,cc,a},{cc,a,b},{cc,b,a}};
    for (int p = 0; p < 6; p++) {
      bool dup = false;
      for (int rr = 0; rr < p; rr++)
        if (pm[rr][0] == pm[p][0] && pm[rr][1] == pm[p][1] && pm[rr][2] == pm[p][2]) dup = true;
      if (!dup) val += U3[ir][(((lo * 9 + pm[p][0]) * 9 + pm[p][1]) * 9 + pm[p][2]) * 6 + j3];
    }
  } else if (ty == 2 && n >= 54 && n < 81) {
    int o = (n - 54) / 3, j2 = (n - 54) % 3;
    int ir = (o > 0) + (o > 3); int lo = o - (ir == 1 ? 1 : (ir == 2 ? 4 : 0));
    val = U2[ir][((lo * 9 + a) * 9 + b) * 3 + j2];
    if (a != b) val += U2[ir][((lo * 9 + b) * 9 + a) * 3 + j2];
  } else if (ty == 1 && n >= 81 && n < 90) {
    int o = n - 81;
    int ir = (o > 0) + (o > 3); int lo = o - (ir == 1 ? 1 : (ir == 2 ? 4 : 0));
    val = U1[ir][lo * 9 + a];
  }
  unsigned u = __float_as_uint(val);
  unsigned r = (u + 0x7FFFu + ((u >> 16) & 1u)) >> 16;   // RNE to bf16
  wsB[t] = (unsigned short)r;
}

// ---- compile-time monomials; paired slots share the (a,b) product ----
template<int Q>
__device__ __forceinline__ float monoQ(const float* xx) {
  if constexpr (SLOTS.ty[Q] == 3)      return xx[SLOTS.a[Q]] * xx[SLOTS.b[Q]] * xx[SLOTS.c[Q]];
  else if constexpr (SLOTS.ty[Q] == 2) return xx[SLOTS.a[Q]] * xx[SLOTS.b[Q]];
  else if constexpr (SLOTS.ty[Q] == 1) return xx[SLOTS.a[Q]];
  else                                 return 0.f;
}

template<int S, int T>
__device__ __forceinline__ float slotval(const float* xx, const int g2) {
  constexpr int Q0 = S * 16 + T, Q1 = S * 16 + 8 + T;
  if constexpr (SLOTS.ty[Q0] == 3 && SLOTS.ty[Q1] == 3 &&
                SLOTS.a[Q0] == SLOTS.a[Q1] && SLOTS.b[Q0] == SLOTS.b[Q1]) {
    // shared pair-product; select only the third factor
    float P = xx[SLOTS.a[Q0]] * xx[SLOTS.b[Q0]];
    float xc = g2 ? xx[SLOTS.c[Q1]] : xx[SLOTS.c[Q0]];
    return P * xc;
  } else {
    return g2 ? monoQ<Q1>(xx) : monoQ<Q0>(xx);
  }
}

template<int S>
__device__ __forceinline__ s16x8 makeB(const float* xx, const int g2) {
  unsigned q0, q1, q2, q3;
  { float lo = slotval<S,0>(xx,g2), hi = slotval<S,1>(xx,g2);
    asm("v_cvt_pk_bf16_f32 %0, %1, %2" : "=v"(q0) : "v"(lo), "v"(hi)); }
  { float lo = slotval<S,2>(xx,g2), hi = slotval<S,3>(xx,g2);
    asm("v_cvt_pk_bf16_f32 %0, %1, %2" : "=v"(q1) : "v"(lo), "v"(hi)); }
  { float lo = slotval<S,4>(xx,g2), hi = slotval<S,5>(xx,g2);
    asm("v_cvt_pk_bf16_f32 %0, %1, %2" : "=v"(q2) : "v"(lo), "v"(hi)); }
  { float lo = slotval<S,6>(xx,g2), hi = slotval<S,7>(xx,g2);
    asm("v_cvt_pk_bf16_f32 %0, %1, %2" : "=v"(q3) : "v"(lo), "v"(hi)); }
  i32x4 bi;
  bi[0] = (int)q0; bi[1] = (int)q1; bi[2] = (int)q2; bi[3] = (int)q3;
  return __builtin_bit_cast(s16x8, bi);
}

// ---- 2-step pipelined k-chain; wv gather issued at S==10 to hide under MFMA tail ----
template<int S>
__device__ __forceinline__ void pipe(const float* xx, const int g2, const i32x4* Uf, const int l,
                                     const float* wbase, float* wv,
                                     f32x16& acc0, f32x16& acc1, f32x16& acc2,
                                     i32x4 c0, i32x4 c1, i32x4 c2,
                                     i32x4 n0, i32x4 n1, i32x4 n2) {
  i32x4 f0{}, f1{}, f2{};
  if constexpr (S + 2 < NSTEP) {
    f0 = Uf[((S + 2) * 3 + 0) * 64 + l];
    f1 = Uf[((S + 2) * 3 + 1) * 64 + l];
    f2 = Uf[((S + 2) * 3 + 2) * 64 + l];
  }
  if constexpr (S == 10) {
#pragma unroll
    for (int p = 0; p < 30; p++) wv[p] = wbase[p * 128];
  }
  s16x8 bf = makeB<S>(xx, g2);
  acc0 = __builtin_amdgcn_mfma_f32_32x32x16_bf16(__builtin_bit_cast(s16x8, c0), bf, acc0, 0, 0, 0);
  acc1 = __builtin_amdgcn_mfma_f32_32x32x16_bf16(__builtin_bit_cast(s16x8, c1), bf, acc1, 0, 0, 0);
  acc2 = __builtin_amdgcn_mfma_f32_32x32x16_bf16(__builtin_bit_cast(s16x8, c2), bf, acc2, 0, 0, 0);
  if constexpr (S + 1 < NSTEP)
    pipe<S + 1>(xx, g2, Uf, l, wbase, wv, acc0, acc1, acc2, n0, n1, n2, f0, f1, f2);
}

#define ACCV(ct) ((ct) == 0 ? acc0 : (ct) == 1 ? acc1 : acc2)

// ---- main: 2048 blocks x 256 threads, zero LDS ----
__global__ __launch_bounds__(256) void symcon_mfma(
    const float* __restrict__ x, const int* __restrict__ indices,
    const float* __restrict__ w, const unsigned short* __restrict__ wsB,
    float* __restrict__ out)
{
  const int tid = threadIdx.x;
  const int wave = tid >> 6;
  const int l = tid & 63;
  const int l5 = l & 31;
  const int g2 = l >> 5;

  const int b = blockIdx.x;
  const int c = wave * 32 + l5;                  // 0..127

  const float* xp = x + ((size_t)b * 128 + c) * 9;
  float xx[9];
#pragma unroll
  for (int i = 0; i < 9; i++) xx[i] = xp[i];

  const int e = indices[b];
  const float* wbase = w + (size_t)e * 30 * 128 + c;
  float wv[30];

  f32x16 acc0, acc1, acc2;
#pragma unroll
  for (int i = 0; i < 16; i++) { acc0[i] = 0.f; acc1[i] = 0.f; acc2[i] = 0.f; }

  const i32x4* Uf = (const i32x4*)wsB;
  i32x4 p0 = Uf[0 * 64 + l], p1 = Uf[1 * 64 + l], p2 = Uf[2 * 64 + l];
  i32x4 r0 = Uf[3 * 64 + l], r1 = Uf[4 * 64 + l], r2 = Uf[5 * 64 + l];
  pipe<0>(xx, g2, Uf, l, wbase, wv, acc0, acc1, acc2, p0, p1, p2, r0, r1, r2);

  // ---- in-register epilogue (R5-validated mapping) ----
  // ACCV(ct)[reg] = D[n = ct*32 + (reg&3) + 8*(reg>>2) + 4*g2][batch = c]
  float* orow = out + (size_t)b * 1152;
#pragma unroll
  for (int o = 0; o < 9; o++) {
    const int ir = (o > 0) + (o > 3);
    float p0f = 0.f, p1f = 0.f;
#pragma unroll
    for (int k3 = 0; k3 < 6; k3++) {
      const int n = 6 * o + k3;
      const int nl = n & 31, ct = n >> 5;
      const int reg = (nl & 3) + 4 * (nl >> 3);
      const float cf = wv[ir * 10 + k3];
      if (((nl >> 2) & 1) == 0) p0f = fmaf(ACCV(ct)[reg], cf, p0f);
      else                      p1f = fmaf(ACCV(ct)[reg], cf, p1f);
    }
#pragma unroll
    for (int k2 = 0; k2 < 3; k2++) {
      const int n = 54 + 3 * o + k2;
      const int nl = n & 31, ct = n >> 5;
      const int reg = (nl & 3) + 4 * (nl >> 3);
      const float cf = wv[ir * 10 + 6 + k2];
      if (((nl >> 2) & 1) == 0) p0f = fmaf(ACCV(ct)[reg], cf, p0f);
      else                      p1f = fmaf(ACCV(ct)[reg], cf, p1f);
    }
    {
      const int n = 81 + o;
      const int nl = n & 31, ct = n >> 5;
      const int reg = (nl & 3) + 4 * (nl >> 3);
      const float cf = wv[ir * 10 + 9];
      if (((nl >> 2) & 1) == 0) p0f = fmaf(ACCV(ct)[reg], cf, p0f);
      else                      p1f = fmaf(ACCV(ct)[reg], cf, p1f);
    }
    float p = g2 ? p1f : p0f;
    p += __shfl_xor(p, 32);
    const int col = (o == 0) ? c : (o < 4 ? 128 + 3 * c + (o - 1) : 512 + 5 * c + (o - 4));
    const bool mine = (o < 5) ? (g2 == 0) : (g2 == 1);
    if (mine) orow[col] = p;
  }
}

extern "C" void kernel_launch(void* const* d_in, const int* in_sizes, int n_in,
                              void* d_out, int out_size, void* d_ws, size_t ws_size,
                              hipStream_t stream) {
  const float* x   = (const float*)d_in[0];
  const int*   idx = (const int*)d_in[1];
  const float* w   = (const float*)d_in[2];
  const float* U30 = (const float*)d_in[3];
  const float* U20 = (const float*)d_in[4];
  const float* U10 = (const float*)d_in[5];
  const float* U31 = (const float*)d_in[6];
  const float* U21 = (const float*)d_in[7];
  const float* U11 = (const float*)d_in[8];
  const float* U32 = (const float*)d_in[9];
  const float* U22 = (const float*)d_in[10];
  const float* U12 = (const float*)d_in[11];
  unsigned short* wsB = (unsigned short*)d_ws;
  float* out = (float*)d_out;

  prep_kernel<<<(UCHUNKS * 8 + 255) / 256, 256, 0, stream>>>(U30, U20, U10, U31, U21, U11, U32, U22, U12, wsB);
  symcon_mfma<<<BATCH, 256, 0, stream>>>(x, idx, w, wsB, out);
}